// Round 4
// baseline (1068.411 us; speedup 1.0000x reference)
//
#include <hip/hip_runtime.h>
#include <stdint.h>

typedef _Float16 f16;
typedef __attribute__((ext_vector_type(8))) _Float16 f16x8;
typedef __attribute__((ext_vector_type(4))) _Float16 f16x4;
typedef __attribute__((ext_vector_type(4))) float f32x4;

// async global->LDS, 16B per lane. LDS dest is wave-uniform base (+lane*16 in HW).
__device__ __forceinline__ void gload16(void* lds, const void* gc) {
  void* g = const_cast<void*>(gc);
  __builtin_amdgcn_global_load_lds((__attribute__((address_space(1))) void*)g,
                                   (__attribute__((address_space(3))) void*)lds,
                                   16, 0, 0);
}

// ---------------- f32 -> f16 cast (plain) ----------------
__global__ __launch_bounds__(256) void k_cast(const float* __restrict__ in,
                                              f16* __restrict__ out, int n4) {
  int stride = gridDim.x * blockDim.x;
  for (int i = blockIdx.x * blockDim.x + threadIdx.x; i < n4; i += stride) {
    float4 v = ((const float4*)in)[i];
    f16x4 o;
    o[0] = (f16)v.x; o[1] = (f16)v.y; o[2] = (f16)v.z; o[3] = (f16)v.w;
    ((f16x4*)out)[i] = o;
  }
}

// ---------------- f32 -> f16 hi + f16 lo split cast ----------------
__global__ __launch_bounds__(256) void k_cast2(const float* __restrict__ in,
                                               f16* __restrict__ hi,
                                               f16* __restrict__ lo, int n4) {
  int stride = gridDim.x * blockDim.x;
  for (int i = blockIdx.x * blockDim.x + threadIdx.x; i < n4; i += stride) {
    float4 v = ((const float4*)in)[i];
    f16x4 h, l;
#pragma unroll
    for (int j = 0; j < 4; ++j) {
      float f = (j == 0) ? v.x : (j == 1) ? v.y : (j == 2) ? v.z : v.w;
      f16 hh = (f16)f;
      h[j] = hh;
      l[j] = (f16)(f - (float)hh);
    }
    ((f16x4*)hi)[i] = h;
    ((f16x4*)lo)[i] = l;
  }
}

// ---------------- V transpose: [BH][L][128] -> [BH][128][L] ----------------
__global__ __launch_bounds__(256) void k_transpose_v(const f16* __restrict__ vp,
                                                     f16* __restrict__ vt) {
  __shared__ __attribute__((aligned(16))) f16 tile[64][66];
  const int lt = blockIdx.x, dt = blockIdx.y, bh = blockIdx.z;
  const int t = threadIdx.x;
  const int r = t >> 3, c = 8 * (t & 7);
  const f16* src = vp + ((size_t)bh * 2048 + lt * 64) * 128 + dt * 64;
#pragma unroll
  for (int i = 0; i < 2; ++i) {
    union { f16x8 v; unsigned u[4]; } uu;
    uu.v = *(const f16x8*)&src[(size_t)(i * 32 + r) * 128 + c];
#pragma unroll
    for (int j = 0; j < 4; ++j)
      *(unsigned*)&tile[i * 32 + r][c + 2 * j] = uu.u[j];
  }
  __syncthreads();
  f16* dst = vt + ((size_t)bh * 128 + dt * 64) * 2048 + lt * 64;
#pragma unroll
  for (int i = 0; i < 2; ++i) {
    const int dr = i * 32 + r;
    f16x8 o;
#pragma unroll
    for (int e = 0; e < 8; ++e) o[e] = tile[c + e][dr];
    *(f16x8*)&dst[(size_t)dr * 2048 + c] = o;
  }
}

// ---------------- NT GEMM: C[M,N] = A[M,K] @ B[N,K]^T, fused epilogues ----------------
// SPLIT=1: A,B have hi/lo pairs; C = Ah Bh^T + Al Bh^T + Ah Bl^T  (~f32 precision)
// EPI 0: QKV  -> outb (hi) [+ outb_lo (lo) if SPLIT] in [B,H,L,DH] layout
// EPI 1: Wo   -> outf = res + C (f32), outb = f16(outf)
// EPI 2: Up   -> outb = f16(relu(C + bias[col]))
// EPI 3: Down -> outf = res + C (f32)
template <int EPI, int SPLIT>
__global__ __launch_bounds__(256) void gemm_nt(const f16* __restrict__ A,
                                               const f16* __restrict__ A_lo,
                                               const f16* __restrict__ B,
                                               const f16* __restrict__ B_lo,
                                               int K, int N,
                                               const float* __restrict__ res,
                                               const float* __restrict__ bias,
                                               float* __restrict__ outf,
                                               f16* __restrict__ outb,
                                               f16* __restrict__ outb_lo) {
  __shared__ __attribute__((aligned(16))) f16 As[(SPLIT ? 2 : 1) * 4096];
  __shared__ __attribute__((aligned(16))) f16 Bs[(SPLIT ? 2 : 1) * 4096];
  const int t = threadIdx.x;
  const int l = t & 63;
  const int w = t >> 6;
  const int wr = w >> 1, wc = w & 1;
  const int bn = blockIdx.x, bm = blockIdx.y;

  f32x4 acc[4][4] = {};

  const size_t aoff = (size_t)bm * 128 * K;
  const size_t boff = (size_t)bn * 128 * K;

  const int srow = t >> 2;       // 0..63 (wave-contiguous)
  const int scol = 8 * (t & 3);  // 0,8,16,24
  const int lbase = w * 512;     // wave-uniform LDS elem offset

  const int lr = l & 15, lq = l >> 4;
  const int nk = K >> 5;
  for (int kt = 0; kt < nk; ++kt) {
    const size_t g0 = (size_t)kt * 32 + (size_t)srow * K + scol;
    const size_t g1 = g0 + (size_t)64 * K;
    gload16(As + lbase,        A + aoff + g0);
    gload16(As + lbase + 2048, A + aoff + g1);
    gload16(Bs + lbase,        B + boff + g0);
    gload16(Bs + lbase + 2048, B + boff + g1);
    if constexpr (SPLIT) {
      gload16(As + 4096 + lbase,        A_lo + aoff + g0);
      gload16(As + 4096 + lbase + 2048, A_lo + aoff + g1);
      gload16(Bs + 4096 + lbase,        B_lo + boff + g0);
      gload16(Bs + 4096 + lbase + 2048, B_lo + boff + g1);
    }
    __syncthreads();
    f16x8 af[4], bfr[4];
#pragma unroll
    for (int m = 0; m < 4; ++m)
      af[m] = *(const f16x8*)&As[(wr * 64 + m * 16 + lr) * 32 + 8 * lq];
#pragma unroll
    for (int n = 0; n < 4; ++n)
      bfr[n] = *(const f16x8*)&Bs[(wc * 64 + n * 16 + lr) * 32 + 8 * lq];
#pragma unroll
    for (int m = 0; m < 4; ++m)
#pragma unroll
      for (int n = 0; n < 4; ++n)
        acc[m][n] = __builtin_amdgcn_mfma_f32_16x16x32_f16(af[m], bfr[n], acc[m][n], 0, 0, 0);
    if constexpr (SPLIT) {
      f16x8 af_lo[4], bf_lo[4];
#pragma unroll
      for (int m = 0; m < 4; ++m)
        af_lo[m] = *(const f16x8*)&As[4096 + (wr * 64 + m * 16 + lr) * 32 + 8 * lq];
#pragma unroll
      for (int n = 0; n < 4; ++n)
        bf_lo[n] = *(const f16x8*)&Bs[4096 + (wc * 64 + n * 16 + lr) * 32 + 8 * lq];
#pragma unroll
      for (int m = 0; m < 4; ++m)
#pragma unroll
        for (int n = 0; n < 4; ++n)
          acc[m][n] = __builtin_amdgcn_mfma_f32_16x16x32_f16(af_lo[m], bfr[n], acc[m][n], 0, 0, 0);
#pragma unroll
      for (int m = 0; m < 4; ++m)
#pragma unroll
        for (int n = 0; n < 4; ++n)
          acc[m][n] = __builtin_amdgcn_mfma_f32_16x16x32_f16(af[m], bf_lo[n], acc[m][n], 0, 0, 0);
    }
    __syncthreads();
  }

#pragma unroll
  for (int m = 0; m < 4; ++m) {
#pragma unroll
    for (int r = 0; r < 4; ++r) {
      const int grow = bm * 128 + wr * 64 + m * 16 + lq * 4 + r;
#pragma unroll
      for (int n = 0; n < 4; ++n) {
        const int gcol = bn * 128 + wc * 64 + n * 16 + lr;
        const float v = acc[m][n][r];
        if constexpr (EPI == 0) {
          const int bb = grow >> 11, ll = grow & 2047;
          const int hh = gcol >> 7, dh = gcol & 127;
          const size_t idx = ((size_t)((bb * 16 + hh) * 2048 + ll) << 7) + dh;
          const f16 hv = (f16)v;
          outb[idx] = hv;
          if constexpr (SPLIT) outb_lo[idx] = (f16)(v - (float)hv);
        } else if constexpr (EPI == 1) {
          const size_t idx = (size_t)grow * N + gcol;
          const float o = res[idx] + v;
          outf[idx] = o;
          outb[idx] = (f16)o;
        } else if constexpr (EPI == 2) {
          const size_t idx = (size_t)grow * N + gcol;
          outb[idx] = (f16)fmaxf(v + bias[gcol], 0.f);
        } else {
          const size_t idx = (size_t)grow * N + gcol;
          outf[idx] = res[idx] + v;
        }
      }
    }
  }
}

// ---------------- causal flash attention (split-precision QK^T) ----------------
// q,k hi/lo: [BH][L][128]; vt: [BH][128][L]; out: [B*L][D] f16
__global__ __launch_bounds__(256) void k_attn(const f16* __restrict__ q_hi,
                                              const f16* __restrict__ q_lo,
                                              const f16* __restrict__ k_hi,
                                              const f16* __restrict__ k_lo,
                                              const f16* __restrict__ vtp,
                                              f16* __restrict__ op) {
  __shared__ __attribute__((aligned(16))) f16 Ks_hi[64 * 136];
  __shared__ __attribute__((aligned(16))) f16 Ks_lo[64 * 136];
  __shared__ __attribute__((aligned(16))) f16 Vs[128 * 72];
  __shared__ __attribute__((aligned(16))) f16 Ps[4][16 * 72];
  const int t = threadIdx.x, l = t & 63, w = t >> 6;
  const int qt = 31 - (int)blockIdx.x;  // heavy blocks first
  const int bh = blockIdx.y;
  const int q0 = qt * 64;
  const int lr = l & 15, lq = l >> 4;

  const f16* qhp = q_hi + (size_t)bh * 2048 * 128;
  const f16* qlp = q_lo + (size_t)bh * 2048 * 128;
  const f16* khp = k_hi + (size_t)bh * 2048 * 128;
  const f16* klp = k_lo + (size_t)bh * 2048 * 128;
  const f16* vhp = vtp + (size_t)bh * 128 * 2048;

  f16x8 aq_hi[4], aq_lo[4];
#pragma unroll
  for (int c = 0; c < 4; ++c) {
    const size_t qi = (size_t)(q0 + w * 16 + lr) * 128 + c * 32 + 8 * lq;
    aq_hi[c] = *(const f16x8*)&qhp[qi];
    aq_lo[c] = *(const f16x8*)&qlp[qi];
  }

  f32x4 acc[8] = {};
  float mrun[4], srun[4];
#pragma unroll
  for (int r = 0; r < 4; ++r) { mrun[r] = -1e30f; srun[r] = 0.f; }

  for (int kt = 0; kt <= qt; ++kt) {
    f16x8 kreg_hi[4], kreg_lo[4], vreg[4];
    const f16* kbh = khp + (size_t)(kt * 64) * 128;
    const f16* kbl = klp + (size_t)(kt * 64) * 128;
    const f16* vb = vhp + kt * 64;
#pragma unroll
    for (int i = 0; i < 4; ++i) {
      const size_t ki = (size_t)(i * 16 + (t >> 4)) * 128 + 8 * (t & 15);
      kreg_hi[i] = *(const f16x8*)&kbh[ki];
      kreg_lo[i] = *(const f16x8*)&kbl[ki];
    }
#pragma unroll
    for (int i = 0; i < 4; ++i)
      vreg[i] = *(const f16x8*)&vb[(size_t)(i * 32 + (t >> 3)) * 2048 + 8 * (t & 7)];
    __syncthreads();  // prior tile's LDS reads done
#pragma unroll
    for (int i = 0; i < 4; ++i) {
      const int li = (i * 16 + (t >> 4)) * 136 + 8 * (t & 15);
      *(f16x8*)&Ks_hi[li] = kreg_hi[i];
      *(f16x8*)&Ks_lo[li] = kreg_lo[i];
    }
#pragma unroll
    for (int i = 0; i < 4; ++i)
      *(f16x8*)&Vs[(i * 32 + (t >> 3)) * 72 + 8 * (t & 7)] = vreg[i];
    __syncthreads();

    // S = Q K^T (split 3-pass: qh*kh + ql*kh + qh*kl)
    f32x4 s[4];
#pragma unroll
    for (int nt = 0; nt < 4; ++nt) {
      f32x4 z = {};
#pragma unroll
      for (int kc = 0; kc < 4; ++kc) {
        const int li = (nt * 16 + lr) * 136 + kc * 32 + 8 * lq;
        f16x8 bh_ = *(const f16x8*)&Ks_hi[li];
        f16x8 bl_ = *(const f16x8*)&Ks_lo[li];
        z = __builtin_amdgcn_mfma_f32_16x16x32_f16(aq_hi[kc], bh_, z, 0, 0, 0);
        z = __builtin_amdgcn_mfma_f32_16x16x32_f16(aq_lo[kc], bh_, z, 0, 0, 0);
        z = __builtin_amdgcn_mfma_f32_16x16x32_f16(aq_hi[kc], bl_, z, 0, 0, 0);
      }
      s[nt] = z;
    }
    if (kt == qt) {  // diagonal tile: causal mask
#pragma unroll
      for (int nt = 0; nt < 4; ++nt)
#pragma unroll
        for (int r = 0; r < 4; ++r) {
          const int key = kt * 64 + nt * 16 + lr;
          const int qr = q0 + w * 16 + lq * 4 + r;
          if (key > qr) s[nt][r] = -1e30f;
        }
    }
    // online softmax (rows live in 16-lane groups; reduce via shfl_xor)
    float mnew[4], scale[4], tsum[4];
#pragma unroll
    for (int r = 0; r < 4; ++r) {
      float mx = fmaxf(fmaxf(s[0][r], s[1][r]), fmaxf(s[2][r], s[3][r]));
#pragma unroll
      for (int off = 1; off < 16; off <<= 1)
        mx = fmaxf(mx, __shfl_xor(mx, off));
      mnew[r] = fmaxf(mrun[r], mx);
      scale[r] = __expf(mrun[r] - mnew[r]);
      mrun[r] = mnew[r];
      tsum[r] = 0.f;
    }
#pragma unroll
    for (int nt = 0; nt < 4; ++nt)
#pragma unroll
      for (int r = 0; r < 4; ++r) {
        const float p = __expf(s[nt][r] - mnew[r]);
        tsum[r] += p;
        Ps[w][(lq * 4 + r) * 72 + nt * 16 + lr] = (f16)p;
      }
#pragma unroll
    for (int r = 0; r < 4; ++r) {
      float ts = tsum[r];
#pragma unroll
      for (int off = 1; off < 16; off <<= 1)
        ts += __shfl_xor(ts, off);
      srun[r] = srun[r] * scale[r] + ts;
    }
#pragma unroll
    for (int nt = 0; nt < 8; ++nt)
#pragma unroll
      for (int r = 0; r < 4; ++r)
        acc[nt][r] *= scale[r];
    // O += P V
#pragma unroll
    for (int kc = 0; kc < 2; ++kc) {
      f16x8 ap = *(const f16x8*)&Ps[w][lr * 72 + kc * 32 + 8 * lq];
#pragma unroll
      for (int nt = 0; nt < 8; ++nt) {
        f16x8 bv = *(const f16x8*)&Vs[(nt * 16 + lr) * 72 + kc * 32 + 8 * lq];
        acc[nt] = __builtin_amdgcn_mfma_f32_16x16x32_f16(ap, bv, acc[nt], 0, 0, 0);
      }
    }
  }
  const int bb = bh >> 4, hh = bh & 15;
#pragma unroll
  for (int r = 0; r < 4; ++r) {
    const float inv = 1.f / srun[r];
    const size_t row = (size_t)(bb * 2048 + q0 + w * 16 + lq * 4 + r);
#pragma unroll
    for (int nt = 0; nt < 8; ++nt)
      op[row * 2048 + hh * 128 + nt * 16 + lr] = (f16)(acc[nt][r] * inv);
  }
}

extern "C" void kernel_launch(void* const* d_in, const int* in_sizes, int n_in,
                              void* d_out, int out_size, void* d_ws, size_t ws_size,
                              hipStream_t stream) {
  const float* x   = (const float*)d_in[0];
  const float* Wq  = (const float*)d_in[2];
  const float* Wk  = (const float*)d_in[3];
  const float* Wv  = (const float*)d_in[4];
  const float* Wo  = (const float*)d_in[5];
  const float* Wup = (const float*)d_in[6];
  const float* bup = (const float*)d_in[7];
  const float* Wdn = (const float*)d_in[8];
  float* out = (float*)d_out;

  const size_t M1 = 1u << 20;
  f16* W = (f16*)d_ws;
  // workspace layout (f16 elements); overlays reuse dead regions.
  f16* x_hi   = W + 0 * M1;    // 8M   x hi
  f16* x_lo   = W + 8 * M1;    // 8M   x lo            (later reused as x1b)
  f16* wq_hi  = W + 16 * M1;   // 4M   dead after Q proj; region reused as hb
  f16* wq_lo  = W + 20 * M1;   // 4M   dead after Q proj
  f16* wk_hi  = W + 24 * M1;   // 4M   dead after K proj
  f16* wk_lo  = W + 28 * M1;   // 4M   dead after K proj
  f16* q_hi   = W + 32 * M1;   // 8M   Q hi, dead after attn
  f16* q_lo   = W + 40 * M1;   // 8M   Q lo, dead after attn
  f16* k_hi   = W + 48 * M1;   // 8M   K hi, dead after attn; region reused as x1f
  f16* k_lo   = W + 56 * M1;   // 8M   K lo, dead after attn
  f16* wv_hi  = W + 64 * M1;   // 4M
  f16* wo_hi  = W + 68 * M1;   // 4M
  f16* wup_hi = W + 72 * M1;   // 16M
  f16* wdn_hi = W + 88 * M1;   // 16M
  f16* vp     = W + 104 * M1;  // 8M   V proj, later attn out
  f16* vtb    = W + 112 * M1;  // 8M   V transposed
  // overlays:
  f16* x1b   = x_lo;
  f16* hb    = wq_hi;                 // 32M region [16M..48M)
  float* x1f = (float*)(W + 48 * M1); // 8M floats  [48M..64M)
  f16* attno = vp;
  if (ws_size < (size_t)120 * M1 * sizeof(f16)) return;  // 240 MB

  auto cg = [](size_t n4) { size_t g = (n4 + 255) / 256; return (unsigned)(g > 4096 ? 4096 : g); };
  dim3 b256(256);
  k_cast2<<<cg(2 * M1), b256, 0, stream>>>(x, x_hi, x_lo, (int)(2 * M1));
  k_cast2<<<cg(1 * M1), b256, 0, stream>>>(Wq, wq_hi, wq_lo, (int)(1 * M1));
  k_cast2<<<cg(1 * M1), b256, 0, stream>>>(Wk, wk_hi, wk_lo, (int)(1 * M1));
  k_cast<<<cg(1 * M1), b256, 0, stream>>>(Wv, wv_hi, (int)(1 * M1));
  k_cast<<<cg(1 * M1), b256, 0, stream>>>(Wo, wo_hi, (int)(1 * M1));
  k_cast<<<cg(4 * M1), b256, 0, stream>>>(Wup, wup_hi, (int)(4 * M1));
  k_cast<<<cg(4 * M1), b256, 0, stream>>>(Wdn, wdn_hi, (int)(4 * M1));

  gemm_nt<0, 1><<<dim3(16, 32), b256, 0, stream>>>(x_hi, x_lo, wq_hi, wq_lo, 2048, 2048, nullptr, nullptr, nullptr, q_hi, q_lo);
  gemm_nt<0, 1><<<dim3(16, 32), b256, 0, stream>>>(x_hi, x_lo, wk_hi, wk_lo, 2048, 2048, nullptr, nullptr, nullptr, k_hi, k_lo);
  gemm_nt<0, 0><<<dim3(16, 32), b256, 0, stream>>>(x_hi, nullptr, wv_hi, nullptr, 2048, 2048, nullptr, nullptr, nullptr, vp, nullptr);
  k_transpose_v<<<dim3(32, 2, 32), b256, 0, stream>>>(vp, vtb);
  k_attn<<<dim3(32, 32), b256, 0, stream>>>(q_hi, q_lo, k_hi, k_lo, vtb, attno);
  gemm_nt<1, 0><<<dim3(16, 32), b256, 0, stream>>>(attno, nullptr, wo_hi, nullptr, 2048, 2048, x, nullptr, x1f, x1b, nullptr);
  gemm_nt<2, 0><<<dim3(64, 32), b256, 0, stream>>>(x1b, nullptr, wup_hi, nullptr, 2048, 8192, nullptr, bup, nullptr, hb, nullptr);
  gemm_nt<3, 0><<<dim3(16, 32), b256, 0, stream>>>(hb, nullptr, wdn_hi, nullptr, 8192, 2048, x1f, nullptr, out, nullptr, nullptr);
}

// Round 5
// 973.344 us; speedup vs baseline: 1.0977x; 1.0977x over previous
//
#include <hip/hip_runtime.h>
#include <stdint.h>

typedef _Float16 f16;
typedef __attribute__((ext_vector_type(8))) _Float16 f16x8;
typedef __attribute__((ext_vector_type(4))) _Float16 f16x4;
typedef __attribute__((ext_vector_type(4))) float f32x4;

// async global->LDS, 16B per lane. LDS dest is wave-uniform base (+lane*16 in HW).
__device__ __forceinline__ void gload16(void* lds, const void* gc) {
  void* g = const_cast<void*>(gc);
  __builtin_amdgcn_global_load_lds((__attribute__((address_space(1))) void*)g,
                                   (__attribute__((address_space(3))) void*)lds,
                                   16, 0, 0);
}

// ---------------- f32 -> f16 cast (plain) ----------------
__global__ __launch_bounds__(256) void k_cast(const float* __restrict__ in,
                                              f16* __restrict__ out, int n4) {
  int stride = gridDim.x * blockDim.x;
  for (int i = blockIdx.x * blockDim.x + threadIdx.x; i < n4; i += stride) {
    float4 v = ((const float4*)in)[i];
    f16x4 o;
    o[0] = (f16)v.x; o[1] = (f16)v.y; o[2] = (f16)v.z; o[3] = (f16)v.w;
    ((f16x4*)out)[i] = o;
  }
}

// ---------------- f32 -> f16 hi + f16 lo split cast ----------------
__global__ __launch_bounds__(256) void k_cast2(const float* __restrict__ in,
                                               f16* __restrict__ hi,
                                               f16* __restrict__ lo, int n4) {
  int stride = gridDim.x * blockDim.x;
  for (int i = blockIdx.x * blockDim.x + threadIdx.x; i < n4; i += stride) {
    float4 v = ((const float4*)in)[i];
    f16x4 h, l;
#pragma unroll
    for (int j = 0; j < 4; ++j) {
      float f = (j == 0) ? v.x : (j == 1) ? v.y : (j == 2) ? v.z : v.w;
      f16 hh = (f16)f;
      h[j] = hh;
      l[j] = (f16)(f - (float)hh);
    }
    ((f16x4*)hi)[i] = h;
    ((f16x4*)lo)[i] = l;
  }
}

// ---------------- V transpose: [BH][L][128] -> [BH][128][L] ----------------
__global__ __launch_bounds__(256) void k_transpose_v(const f16* __restrict__ vp,
                                                     f16* __restrict__ vt) {
  __shared__ __attribute__((aligned(16))) f16 tile[64][66];
  const int lt = blockIdx.x, dt = blockIdx.y, bh = blockIdx.z;
  const int t = threadIdx.x;
  const int r = t >> 3, c = 8 * (t & 7);
  const f16* src = vp + ((size_t)bh * 2048 + lt * 64) * 128 + dt * 64;
#pragma unroll
  for (int i = 0; i < 2; ++i) {
    union { f16x8 v; unsigned u[4]; } uu;
    uu.v = *(const f16x8*)&src[(size_t)(i * 32 + r) * 128 + c];
#pragma unroll
    for (int j = 0; j < 4; ++j)
      *(unsigned*)&tile[i * 32 + r][c + 2 * j] = uu.u[j];
  }
  __syncthreads();
  f16* dst = vt + ((size_t)bh * 128 + dt * 64) * 2048 + lt * 64;
#pragma unroll
  for (int i = 0; i < 2; ++i) {
    const int dr = i * 32 + r;
    f16x8 o;
#pragma unroll
    for (int e = 0; e < 8; ++e) o[e] = tile[c + e][dr];
    *(f16x8*)&dst[(size_t)dr * 2048 + c] = o;
  }
}

// ---------------- final fuse: out = f32(x1b) + p0 + p1 ----------------
__global__ __launch_bounds__(256) void k_fuseout(const f16* __restrict__ x1b,
                                                 const float* __restrict__ p0,
                                                 const float* __restrict__ p1,
                                                 float* __restrict__ out, int n4) {
  int stride = gridDim.x * blockDim.x;
  for (int i = blockIdx.x * blockDim.x + threadIdx.x; i < n4; i += stride) {
    float4 a = ((const float4*)p0)[i];
    float4 b = ((const float4*)p1)[i];
    f16x4 xb = ((const f16x4*)x1b)[i];
    float4 o;
    o.x = (float)xb[0] + a.x + b.x;
    o.y = (float)xb[1] + a.y + b.y;
    o.z = (float)xb[2] + a.z + b.z;
    o.w = (float)xb[3] + a.w + b.w;
    ((float4*)out)[i] = o;
  }
}

// ---------------- NT GEMM: C[M,N] = A[M,K] @ B[N,K]^T, fused epilogues ----------------
// SPLIT=1: A,B have hi/lo pairs; C = Ah Bh^T + Al Bh^T + Ah Bl^T  (~f32 precision)
// EPI 0: QKV-style -> outb (hi) [+ outb_lo if SPLIT] in [which][B,H,L,DH] layout
//        (which = gcol>>11; for N=2048 which==0 always)
// EPI 1: Wo   -> outb = f16(res[idx] + C)
// EPI 2: Up   -> outb = f16(relu(C + bias[col]))
// EPI 3: Down partial -> (z ? outf2 : outf)[idx] = C   (f32, no residual)
// Kit = K elements iterated by this block; ld = row stride of A and B;
// blockIdx.z selects K-chunk z*Kit.
template <int EPI, int SPLIT, int BK>
__global__ __launch_bounds__(256, 4) void gemm_nt(const f16* __restrict__ A,
                                                  const f16* __restrict__ A_lo,
                                                  const f16* __restrict__ B,
                                                  const f16* __restrict__ B_lo,
                                                  int Kit, int ld, int N,
                                                  const float* __restrict__ res,
                                                  const float* __restrict__ bias,
                                                  float* __restrict__ outf,
                                                  float* __restrict__ outf2,
                                                  f16* __restrict__ outb,
                                                  f16* __restrict__ outb_lo) {
  constexpr int TSZ = 128 * BK;       // tile elems per matrix
  constexpr int CH  = 2048;           // elems staged per chunk (256 thr x 8)
  constexpr int RPC = CH / BK;        // rows per chunk
  constexpr int NCH = 128 / RPC;      // chunks per tile
  constexpr int CW  = BK / 8;         // threads per staged row
  __shared__ __attribute__((aligned(16))) f16 As[(SPLIT ? 2 : 1) * TSZ];
  __shared__ __attribute__((aligned(16))) f16 Bs[(SPLIT ? 2 : 1) * TSZ];
  const int t = threadIdx.x;
  const int l = t & 63;
  const int w = t >> 6;
  const int wr = w >> 1, wc = w & 1;

  // XCD-aware bijective swizzle (nwg % 8 == 0 for all our grids)
  const int nwg = gridDim.x * gridDim.y;
  const int id = blockIdx.y * gridDim.x + blockIdx.x;
  const int sw = (id & 7) * (nwg >> 3) + (id >> 3);
  const int bn = sw % gridDim.x;
  const int bm = sw / gridDim.x;
  const int k0 = blockIdx.z * Kit;

  f32x4 acc[4][4] = {};

  const size_t aoff = (size_t)bm * 128 * ld + k0;
  const size_t boff = (size_t)bn * 128 * ld + k0;

  const int sr = t / CW;            // staged row within chunk
  const int sc = 8 * (t % CW);      // staged col
  const int lbase = w * 512;        // wave-uniform LDS elem offset

  const int lr = l & 15, lq = l >> 4;
  const int nk = Kit / BK;
  for (int kt = 0; kt < nk; ++kt) {
    const size_t gbase = (size_t)kt * BK + (size_t)sr * ld + sc;
#pragma unroll
    for (int j = 0; j < NCH; ++j) {
      gload16(As + j * CH + lbase, A + aoff + (size_t)j * RPC * ld + gbase);
      gload16(Bs + j * CH + lbase, B + boff + (size_t)j * RPC * ld + gbase);
    }
    if constexpr (SPLIT) {
#pragma unroll
      for (int j = 0; j < NCH; ++j) {
        gload16(As + TSZ + j * CH + lbase, A_lo + aoff + (size_t)j * RPC * ld + gbase);
        gload16(Bs + TSZ + j * CH + lbase, B_lo + boff + (size_t)j * RPC * ld + gbase);
      }
    }
    __syncthreads();
#pragma unroll
    for (int kk = 0; kk < BK / 32; ++kk) {
      f16x8 af[4], bfr[4];
#pragma unroll
      for (int m = 0; m < 4; ++m)
        af[m] = *(const f16x8*)&As[(wr * 64 + m * 16 + lr) * BK + kk * 32 + 8 * lq];
#pragma unroll
      for (int n = 0; n < 4; ++n)
        bfr[n] = *(const f16x8*)&Bs[(wc * 64 + n * 16 + lr) * BK + kk * 32 + 8 * lq];
#pragma unroll
      for (int m = 0; m < 4; ++m)
#pragma unroll
        for (int n = 0; n < 4; ++n)
          acc[m][n] = __builtin_amdgcn_mfma_f32_16x16x32_f16(af[m], bfr[n], acc[m][n], 0, 0, 0);
      if constexpr (SPLIT) {
        f16x8 af_lo[4], bf_lo[4];
#pragma unroll
        for (int m = 0; m < 4; ++m)
          af_lo[m] = *(const f16x8*)&As[TSZ + (wr * 64 + m * 16 + lr) * BK + kk * 32 + 8 * lq];
#pragma unroll
        for (int n = 0; n < 4; ++n)
          bf_lo[n] = *(const f16x8*)&Bs[TSZ + (wc * 64 + n * 16 + lr) * BK + kk * 32 + 8 * lq];
#pragma unroll
        for (int m = 0; m < 4; ++m)
#pragma unroll
          for (int n = 0; n < 4; ++n)
            acc[m][n] = __builtin_amdgcn_mfma_f32_16x16x32_f16(af_lo[m], bfr[n], acc[m][n], 0, 0, 0);
#pragma unroll
        for (int m = 0; m < 4; ++m)
#pragma unroll
          for (int n = 0; n < 4; ++n)
            acc[m][n] = __builtin_amdgcn_mfma_f32_16x16x32_f16(af[m], bf_lo[n], acc[m][n], 0, 0, 0);
      }
    }
    __syncthreads();
  }

  const size_t QKS = (size_t)8 << 20;  // stride between fused output matrices
#pragma unroll
  for (int m = 0; m < 4; ++m) {
#pragma unroll
    for (int r = 0; r < 4; ++r) {
      const int grow = bm * 128 + wr * 64 + m * 16 + lq * 4 + r;
#pragma unroll
      for (int n = 0; n < 4; ++n) {
        const int gcol = bn * 128 + wc * 64 + n * 16 + lr;
        const float v = acc[m][n][r];
        if constexpr (EPI == 0) {
          const int which = gcol >> 11;
          const int hcol = gcol & 2047;
          const int bb = grow >> 11, ll = grow & 2047;
          const int hh = hcol >> 7, dh = hcol & 127;
          const size_t idx = which * QKS + ((size_t)((bb * 16 + hh) * 2048 + ll) << 7) + dh;
          const f16 hv = (f16)v;
          outb[idx] = hv;
          if constexpr (SPLIT) outb_lo[idx] = (f16)(v - (float)hv);
        } else if constexpr (EPI == 1) {
          const size_t idx = (size_t)grow * N + gcol;
          outb[idx] = (f16)(res[idx] + v);
        } else if constexpr (EPI == 2) {
          const size_t idx = (size_t)grow * N + gcol;
          outb[idx] = (f16)fmaxf(v + bias[gcol], 0.f);
        } else {
          const size_t idx = (size_t)grow * N + gcol;
          (blockIdx.z ? outf2 : outf)[idx] = v;
        }
      }
    }
  }
}

// ---------------- causal flash attention (split-precision QK^T) ----------------
// q,k hi/lo: [BH][L][128]; vt: [BH][128][L]; out: [B*L][D] f16
__global__ __launch_bounds__(256) void k_attn(const f16* __restrict__ q_hi,
                                              const f16* __restrict__ q_lo,
                                              const f16* __restrict__ k_hi,
                                              const f16* __restrict__ k_lo,
                                              const f16* __restrict__ vtp,
                                              f16* __restrict__ op) {
  __shared__ __attribute__((aligned(16))) f16 Ks_hi[64 * 136];
  __shared__ __attribute__((aligned(16))) f16 Ks_lo[64 * 136];
  __shared__ __attribute__((aligned(16))) f16 Vs[128 * 72];
  __shared__ __attribute__((aligned(16))) f16 Ps[4][16 * 72];
  const int t = threadIdx.x, l = t & 63, w = t >> 6;
  const int qt = 31 - (int)blockIdx.x;  // heavy blocks first
  const int bh = blockIdx.y;
  const int q0 = qt * 64;
  const int lr = l & 15, lq = l >> 4;

  const f16* qhp = q_hi + (size_t)bh * 2048 * 128;
  const f16* qlp = q_lo + (size_t)bh * 2048 * 128;
  const f16* khp = k_hi + (size_t)bh * 2048 * 128;
  const f16* klp = k_lo + (size_t)bh * 2048 * 128;
  const f16* vhp = vtp + (size_t)bh * 128 * 2048;

  f16x8 aq_hi[4], aq_lo[4];
#pragma unroll
  for (int c = 0; c < 4; ++c) {
    const size_t qi = (size_t)(q0 + w * 16 + lr) * 128 + c * 32 + 8 * lq;
    aq_hi[c] = *(const f16x8*)&qhp[qi];
    aq_lo[c] = *(const f16x8*)&qlp[qi];
  }

  f32x4 acc[8] = {};
  float mrun[4], srun[4];
#pragma unroll
  for (int r = 0; r < 4; ++r) { mrun[r] = -1e30f; srun[r] = 0.f; }

  for (int kt = 0; kt <= qt; ++kt) {
    f16x8 kreg_hi[4], kreg_lo[4], vreg[4];
    const f16* kbh = khp + (size_t)(kt * 64) * 128;
    const f16* kbl = klp + (size_t)(kt * 64) * 128;
    const f16* vb = vhp + kt * 64;
#pragma unroll
    for (int i = 0; i < 4; ++i) {
      const size_t ki = (size_t)(i * 16 + (t >> 4)) * 128 + 8 * (t & 15);
      kreg_hi[i] = *(const f16x8*)&kbh[ki];
      kreg_lo[i] = *(const f16x8*)&kbl[ki];
    }
#pragma unroll
    for (int i = 0; i < 4; ++i)
      vreg[i] = *(const f16x8*)&vb[(size_t)(i * 32 + (t >> 3)) * 2048 + 8 * (t & 7)];
    __syncthreads();  // prior tile's LDS reads done
#pragma unroll
    for (int i = 0; i < 4; ++i) {
      const int li = (i * 16 + (t >> 4)) * 136 + 8 * (t & 15);
      *(f16x8*)&Ks_hi[li] = kreg_hi[i];
      *(f16x8*)&Ks_lo[li] = kreg_lo[i];
    }
#pragma unroll
    for (int i = 0; i < 4; ++i)
      *(f16x8*)&Vs[(i * 32 + (t >> 3)) * 72 + 8 * (t & 7)] = vreg[i];
    __syncthreads();

    // S = Q K^T (split 3-pass: qh*kh + ql*kh + qh*kl)
    f32x4 s[4];
#pragma unroll
    for (int nt = 0; nt < 4; ++nt) {
      f32x4 z = {};
#pragma unroll
      for (int kc = 0; kc < 4; ++kc) {
        const int li = (nt * 16 + lr) * 136 + kc * 32 + 8 * lq;
        f16x8 bh_ = *(const f16x8*)&Ks_hi[li];
        f16x8 bl_ = *(const f16x8*)&Ks_lo[li];
        z = __builtin_amdgcn_mfma_f32_16x16x32_f16(aq_hi[kc], bh_, z, 0, 0, 0);
        z = __builtin_amdgcn_mfma_f32_16x16x32_f16(aq_lo[kc], bh_, z, 0, 0, 0);
        z = __builtin_amdgcn_mfma_f32_16x16x32_f16(aq_hi[kc], bl_, z, 0, 0, 0);
      }
      s[nt] = z;
    }
    if (kt == qt) {  // diagonal tile: causal mask
#pragma unroll
      for (int nt = 0; nt < 4; ++nt)
#pragma unroll
        for (int r = 0; r < 4; ++r) {
          const int key = kt * 64 + nt * 16 + lr;
          const int qr = q0 + w * 16 + lq * 4 + r;
          if (key > qr) s[nt][r] = -1e30f;
        }
    }
    // online softmax (rows live in 16-lane groups; reduce via shfl_xor)
    float mnew[4], scale[4], tsum[4];
#pragma unroll
    for (int r = 0; r < 4; ++r) {
      float mx = fmaxf(fmaxf(s[0][r], s[1][r]), fmaxf(s[2][r], s[3][r]));
#pragma unroll
      for (int off = 1; off < 16; off <<= 1)
        mx = fmaxf(mx, __shfl_xor(mx, off));
      mnew[r] = fmaxf(mrun[r], mx);
      scale[r] = __expf(mrun[r] - mnew[r]);
      mrun[r] = mnew[r];
      tsum[r] = 0.f;
    }
#pragma unroll
    for (int nt = 0; nt < 4; ++nt)
#pragma unroll
      for (int r = 0; r < 4; ++r) {
        const float p = __expf(s[nt][r] - mnew[r]);
        tsum[r] += p;
        Ps[w][(lq * 4 + r) * 72 + nt * 16 + lr] = (f16)p;
      }
#pragma unroll
    for (int r = 0; r < 4; ++r) {
      float ts = tsum[r];
#pragma unroll
      for (int off = 1; off < 16; off <<= 1)
        ts += __shfl_xor(ts, off);
      srun[r] = srun[r] * scale[r] + ts;
    }
#pragma unroll
    for (int nt = 0; nt < 8; ++nt)
#pragma unroll
      for (int r = 0; r < 4; ++r)
        acc[nt][r] *= scale[r];
    // O += P V
#pragma unroll
    for (int kc = 0; kc < 2; ++kc) {
      f16x8 ap = *(const f16x8*)&Ps[w][lr * 72 + kc * 32 + 8 * lq];
#pragma unroll
      for (int nt = 0; nt < 8; ++nt) {
        f16x8 bv = *(const f16x8*)&Vs[(nt * 16 + lr) * 72 + kc * 32 + 8 * lq];
        acc[nt] = __builtin_amdgcn_mfma_f32_16x16x32_f16(ap, bv, acc[nt], 0, 0, 0);
      }
    }
  }
  const int bb = bh >> 4, hh = bh & 15;
#pragma unroll
  for (int r = 0; r < 4; ++r) {
    const float inv = 1.f / srun[r];
    const size_t row = (size_t)(bb * 2048 + q0 + w * 16 + lq * 4 + r);
#pragma unroll
    for (int nt = 0; nt < 8; ++nt)
      op[row * 2048 + hh * 128 + nt * 16 + lr] = (f16)(acc[nt][r] * inv);
  }
}

extern "C" void kernel_launch(void* const* d_in, const int* in_sizes, int n_in,
                              void* d_out, int out_size, void* d_ws, size_t ws_size,
                              hipStream_t stream) {
  const float* x   = (const float*)d_in[0];
  const float* Wq  = (const float*)d_in[2];
  const float* Wk  = (const float*)d_in[3];
  const float* Wv  = (const float*)d_in[4];
  const float* Wo  = (const float*)d_in[5];
  const float* Wup = (const float*)d_in[6];
  const float* bup = (const float*)d_in[7];
  const float* Wdn = (const float*)d_in[8];
  float* out = (float*)d_out;

  const size_t M1 = 1u << 20;
  f16* W = (f16*)d_ws;
  // workspace layout (units of M1 f16 elems); overlays reuse dead regions:
  //  [0..8)    x_hi                      dead after V-proj
  //  [8..16)   x_lo (dead after QK)  ->  x1b (written at Wo)
  //  [16..32)  wqk_hi+wqk_lo (dead after QK) -> p0 (f32, 8M floats)
  //  [32..48)  qk_hi  (Q at 32, K at 40; dead after attn) -> hb low half
  //  [48..64)  qk_lo  (Q at 48, K at 56; dead after attn) -> hb high half
  //  [64..68)  wv_hi;  [68..72) wo_hi
  //  [72..88)  wup_hi (dead after Up) -> p1 (f32, 8M floats)
  //  [88..104) wdn_hi
  //  [104..112) vp (V proj; later attn out)
  //  [112..120) vtb (V transposed; dead after attn)
  f16* x_hi   = W + 0 * M1;
  f16* x_lo   = W + 8 * M1;
  f16* wqk_hi = W + 16 * M1;
  f16* wqk_lo = W + 24 * M1;
  f16* qk_hi  = W + 32 * M1;
  f16* qk_lo  = W + 48 * M1;
  f16* wv_hi  = W + 64 * M1;
  f16* wo_hi  = W + 68 * M1;
  f16* wup_hi = W + 72 * M1;
  f16* wdn_hi = W + 88 * M1;
  f16* vp     = W + 104 * M1;
  f16* vtb    = W + 112 * M1;
  // overlays:
  f16* x1b   = x_lo;
  float* p0  = (float*)(W + 16 * M1);
  f16* hb    = W + 32 * M1;
  float* p1  = (float*)(W + 72 * M1);
  f16* attno = vp;
  if (ws_size < (size_t)120 * M1 * sizeof(f16)) return;  // 240 MB

  auto cg = [](size_t n4) { size_t g = (n4 + 255) / 256; return (unsigned)(g > 2048 ? 2048 : g); };
  dim3 b256(256);
  k_cast2<<<cg(2 * M1), b256, 0, stream>>>(x, x_hi, x_lo, (int)(2 * M1));
  k_cast2<<<cg(1 * M1), b256, 0, stream>>>(Wq, wqk_hi, wqk_lo, (int)(1 * M1));
  k_cast2<<<cg(1 * M1), b256, 0, stream>>>(Wk, wqk_hi + 4 * M1, wqk_lo + 4 * M1, (int)(1 * M1));
  k_cast<<<cg(1 * M1), b256, 0, stream>>>(Wv, wv_hi, (int)(1 * M1));
  k_cast<<<cg(1 * M1), b256, 0, stream>>>(Wo, wo_hi, (int)(1 * M1));
  k_cast<<<cg(4 * M1), b256, 0, stream>>>(Wup, wup_hi, (int)(4 * M1));
  k_cast<<<cg(4 * M1), b256, 0, stream>>>(Wdn, wdn_hi, (int)(4 * M1));

  // fused Q+K projection (split 3-pass), N=4096 -> 1024 blocks
  gemm_nt<0, 1, 32><<<dim3(32, 32), b256, 0, stream>>>(
      x_hi, x_lo, wqk_hi, wqk_lo, 2048, 2048, 4096,
      nullptr, nullptr, nullptr, nullptr, qk_hi, qk_lo);
  // V projection
  gemm_nt<0, 0, 64><<<dim3(16, 32), b256, 0, stream>>>(
      x_hi, nullptr, wv_hi, nullptr, 2048, 2048, 2048,
      nullptr, nullptr, nullptr, nullptr, vp, nullptr);
  k_transpose_v<<<dim3(32, 2, 32), b256, 0, stream>>>(vp, vtb);
  k_attn<<<dim3(32, 32), b256, 0, stream>>>(
      qk_hi, qk_lo, qk_hi + 8 * M1, qk_lo + 8 * M1, vtb, attno);
  // Wo projection + residual -> x1b (f16)
  gemm_nt<1, 0, 64><<<dim3(16, 32), b256, 0, stream>>>(
      attno, nullptr, wo_hi, nullptr, 2048, 2048, 2048,
      x, nullptr, nullptr, nullptr, x1b, nullptr);
  // Up + bias + relu -> hb
  gemm_nt<2, 0, 64><<<dim3(64, 32), b256, 0, stream>>>(
      x1b, nullptr, wup_hi, nullptr, 2048, 2048, 8192,
      nullptr, bup, nullptr, nullptr, hb, nullptr);
  // Down, K split 2x -> f32 partials
  gemm_nt<3, 0, 64><<<dim3(16, 32, 2), b256, 0, stream>>>(
      hb, nullptr, wdn_hi, nullptr, 4096, 8192, 2048,
      nullptr, nullptr, p0, p1, nullptr, nullptr);
  // out = f32(x1b) + p0 + p1
  k_fuseout<<<2048, b256, 0, stream>>>(x1b, p0, p1, out, (int)(2 * M1));
}

// Round 6
// 968.544 us; speedup vs baseline: 1.1031x; 1.0050x over previous
//
#include <hip/hip_runtime.h>
#include <stdint.h>

typedef _Float16 f16;
typedef __attribute__((ext_vector_type(8))) _Float16 f16x8;
typedef __attribute__((ext_vector_type(4))) _Float16 f16x4;
typedef __attribute__((ext_vector_type(4))) float f32x4;

// async global->LDS, 16B per lane. LDS dest is wave-uniform base (+lane*16 in HW).
__device__ __forceinline__ void gload16(void* lds, const void* gc) {
  void* g = const_cast<void*>(gc);
  __builtin_amdgcn_global_load_lds((__attribute__((address_space(1))) void*)g,
                                   (__attribute__((address_space(3))) void*)lds,
                                   16, 0, 0);
}

// ---------------- f32 -> f16 cast (plain) ----------------
__global__ __launch_bounds__(256) void k_cast(const float* __restrict__ in,
                                              f16* __restrict__ out, int n4) {
  int stride = gridDim.x * blockDim.x;
  for (int i = blockIdx.x * blockDim.x + threadIdx.x; i < n4; i += stride) {
    float4 v = ((const float4*)in)[i];
    f16x4 o;
    o[0] = (f16)v.x; o[1] = (f16)v.y; o[2] = (f16)v.z; o[3] = (f16)v.w;
    ((f16x4*)out)[i] = o;
  }
}

// ---------------- f32 -> f16 hi + f16 lo split cast ----------------
__global__ __launch_bounds__(256) void k_cast2(const float* __restrict__ in,
                                               f16* __restrict__ hi,
                                               f16* __restrict__ lo, int n4) {
  int stride = gridDim.x * blockDim.x;
  for (int i = blockIdx.x * blockDim.x + threadIdx.x; i < n4; i += stride) {
    float4 v = ((const float4*)in)[i];
    f16x4 h, l;
#pragma unroll
    for (int j = 0; j < 4; ++j) {
      float f = (j == 0) ? v.x : (j == 1) ? v.y : (j == 2) ? v.z : v.w;
      f16 hh = (f16)f;
      h[j] = hh;
      l[j] = (f16)(f - (float)hh);
    }
    ((f16x4*)hi)[i] = h;
    ((f16x4*)lo)[i] = l;
  }
}

// ---------------- V transpose: [BH][L][128] -> [BH][128][L] ----------------
__global__ __launch_bounds__(256) void k_transpose_v(const f16* __restrict__ vp,
                                                     f16* __restrict__ vt) {
  __shared__ __attribute__((aligned(16))) f16 tile[64][66];
  const int lt = blockIdx.x, dt = blockIdx.y, bh = blockIdx.z;
  const int t = threadIdx.x;
  const int r = t >> 3, c = 8 * (t & 7);
  const f16* src = vp + ((size_t)bh * 2048 + lt * 64) * 128 + dt * 64;
#pragma unroll
  for (int i = 0; i < 2; ++i) {
    union { f16x8 v; unsigned u[4]; } uu;
    uu.v = *(const f16x8*)&src[(size_t)(i * 32 + r) * 128 + c];
#pragma unroll
    for (int j = 0; j < 4; ++j)
      *(unsigned*)&tile[i * 32 + r][c + 2 * j] = uu.u[j];
  }
  __syncthreads();
  f16* dst = vt + ((size_t)bh * 128 + dt * 64) * 2048 + lt * 64;
#pragma unroll
  for (int i = 0; i < 2; ++i) {
    const int dr = i * 32 + r;
    f16x8 o;
#pragma unroll
    for (int e = 0; e < 8; ++e) o[e] = tile[c + e][dr];
    *(f16x8*)&dst[(size_t)dr * 2048 + c] = o;
  }
}

// ---------------- final fuse: out = f32(x1b) + p0 + p1 ----------------
__global__ __launch_bounds__(256) void k_fuseout(const f16* __restrict__ x1b,
                                                 const float* __restrict__ p0,
                                                 const float* __restrict__ p1,
                                                 float* __restrict__ out, int n4) {
  int stride = gridDim.x * blockDim.x;
  for (int i = blockIdx.x * blockDim.x + threadIdx.x; i < n4; i += stride) {
    float4 a = ((const float4*)p0)[i];
    float4 b = ((const float4*)p1)[i];
    f16x4 xb = ((const f16x4*)x1b)[i];
    float4 o;
    o.x = (float)xb[0] + a.x + b.x;
    o.y = (float)xb[1] + a.y + b.y;
    o.z = (float)xb[2] + a.z + b.z;
    o.w = (float)xb[3] + a.w + b.w;
    ((float4*)out)[i] = o;
  }
}

// ---------------- NT GEMM: C[M,N] = A[M,K] @ B[N,K]^T, fused epilogues ----------------
// SPLIT=1: A,B have hi/lo pairs; C = Ah Bh^T + Al Bh^T + Ah Bl^T  (~f32 precision)
// EPI 0: QKV-style -> outb (hi) [+ outb_lo if SPLIT] in [which][B,H,L,DH] layout
//        (which = gcol>>11; for N=2048 which==0 always)
// EPI 1: Wo   -> outb = f16(res[idx] + C)
// EPI 2: Up   -> outb = f16(relu(C + bias[col]))
// EPI 3: Down partial -> (z ? outf2 : outf)[idx] = C   (f32, no residual)
// Kit = K elements iterated by this block; ld = row stride of A and B;
// blockIdx.z selects K-chunk z*Kit.
template <int EPI, int SPLIT, int BK>
__global__ __launch_bounds__(256, 4) void gemm_nt(const f16* __restrict__ A,
                                                  const f16* __restrict__ A_lo,
                                                  const f16* __restrict__ B,
                                                  const f16* __restrict__ B_lo,
                                                  int Kit, int ld, int N,
                                                  const float* __restrict__ res,
                                                  const float* __restrict__ bias,
                                                  float* __restrict__ outf,
                                                  float* __restrict__ outf2,
                                                  f16* __restrict__ outb,
                                                  f16* __restrict__ outb_lo) {
  constexpr int TSZ = 128 * BK;       // tile elems per matrix
  constexpr int CH  = 2048;           // elems staged per chunk (256 thr x 8)
  constexpr int RPC = CH / BK;        // rows per chunk
  constexpr int NCH = 128 / RPC;      // chunks per tile
  constexpr int CW  = BK / 8;         // threads per staged row
  __shared__ __attribute__((aligned(16))) f16 As[(SPLIT ? 2 : 1) * TSZ];
  __shared__ __attribute__((aligned(16))) f16 Bs[(SPLIT ? 2 : 1) * TSZ];
  const int t = threadIdx.x;
  const int l = t & 63;
  const int w = t >> 6;
  const int wr = w >> 1, wc = w & 1;

  // XCD-aware bijective swizzle (nwg % 8 == 0 for all our grids)
  const int nwg = gridDim.x * gridDim.y;
  const int id = blockIdx.y * gridDim.x + blockIdx.x;
  const int sw = (id & 7) * (nwg >> 3) + (id >> 3);
  const int bn = sw % gridDim.x;
  const int bm = sw / gridDim.x;
  const int k0 = blockIdx.z * Kit;

  f32x4 acc[4][4] = {};

  const size_t aoff = (size_t)bm * 128 * ld + k0;
  const size_t boff = (size_t)bn * 128 * ld + k0;

  const int sr = t / CW;            // staged row within chunk
  const int sc = 8 * (t % CW);      // staged col
  const int lbase = w * 512;        // wave-uniform LDS elem offset

  const int lr = l & 15, lq = l >> 4;
  const int nk = Kit / BK;
  for (int kt = 0; kt < nk; ++kt) {
    const size_t gbase = (size_t)kt * BK + (size_t)sr * ld + sc;
#pragma unroll
    for (int j = 0; j < NCH; ++j) {
      gload16(As + j * CH + lbase, A + aoff + (size_t)j * RPC * ld + gbase);
      gload16(Bs + j * CH + lbase, B + boff + (size_t)j * RPC * ld + gbase);
    }
    if constexpr (SPLIT) {
#pragma unroll
      for (int j = 0; j < NCH; ++j) {
        gload16(As + TSZ + j * CH + lbase, A_lo + aoff + (size_t)j * RPC * ld + gbase);
        gload16(Bs + TSZ + j * CH + lbase, B_lo + boff + (size_t)j * RPC * ld + gbase);
      }
    }
    __syncthreads();
#pragma unroll
    for (int kk = 0; kk < BK / 32; ++kk) {
      f16x8 af[4], bfr[4];
#pragma unroll
      for (int m = 0; m < 4; ++m)
        af[m] = *(const f16x8*)&As[(wr * 64 + m * 16 + lr) * BK + kk * 32 + 8 * lq];
#pragma unroll
      for (int n = 0; n < 4; ++n)
        bfr[n] = *(const f16x8*)&Bs[(wc * 64 + n * 16 + lr) * BK + kk * 32 + 8 * lq];
#pragma unroll
      for (int m = 0; m < 4; ++m)
#pragma unroll
        for (int n = 0; n < 4; ++n)
          acc[m][n] = __builtin_amdgcn_mfma_f32_16x16x32_f16(af[m], bfr[n], acc[m][n], 0, 0, 0);
      if constexpr (SPLIT) {
        f16x8 af_lo[4], bf_lo[4];
#pragma unroll
        for (int m = 0; m < 4; ++m)
          af_lo[m] = *(const f16x8*)&As[TSZ + (wr * 64 + m * 16 + lr) * BK + kk * 32 + 8 * lq];
#pragma unroll
        for (int n = 0; n < 4; ++n)
          bf_lo[n] = *(const f16x8*)&Bs[TSZ + (wc * 64 + n * 16 + lr) * BK + kk * 32 + 8 * lq];
#pragma unroll
        for (int m = 0; m < 4; ++m)
#pragma unroll
          for (int n = 0; n < 4; ++n)
            acc[m][n] = __builtin_amdgcn_mfma_f32_16x16x32_f16(af_lo[m], bfr[n], acc[m][n], 0, 0, 0);
#pragma unroll
        for (int m = 0; m < 4; ++m)
#pragma unroll
          for (int n = 0; n < 4; ++n)
            acc[m][n] = __builtin_amdgcn_mfma_f32_16x16x32_f16(af[m], bf_lo[n], acc[m][n], 0, 0, 0);
      }
    }
    __syncthreads();
  }

  const size_t QKS = (size_t)8 << 20;  // stride between fused output matrices
#pragma unroll
  for (int m = 0; m < 4; ++m) {
#pragma unroll
    for (int r = 0; r < 4; ++r) {
      const int grow = bm * 128 + wr * 64 + m * 16 + lq * 4 + r;
#pragma unroll
      for (int n = 0; n < 4; ++n) {
        const int gcol = bn * 128 + wc * 64 + n * 16 + lr;
        const float v = acc[m][n][r];
        if constexpr (EPI == 0) {
          const int which = gcol >> 11;
          const int hcol = gcol & 2047;
          const int bb = grow >> 11, ll = grow & 2047;
          const int hh = hcol >> 7, dh = hcol & 127;
          const size_t idx = which * QKS + ((size_t)((bb * 16 + hh) * 2048 + ll) << 7) + dh;
          const f16 hv = (f16)v;
          outb[idx] = hv;
          if constexpr (SPLIT) outb_lo[idx] = (f16)(v - (float)hv);
        } else if constexpr (EPI == 1) {
          const size_t idx = (size_t)grow * N + gcol;
          outb[idx] = (f16)(res[idx] + v);
        } else if constexpr (EPI == 2) {
          const size_t idx = (size_t)grow * N + gcol;
          outb[idx] = (f16)fmaxf(v + bias[gcol], 0.f);
        } else {
          const size_t idx = (size_t)grow * N + gcol;
          (blockIdx.z ? outf2 : outf)[idx] = v;
        }
      }
    }
  }
}

// ---------------- causal flash attention (split-precision QK^T, pipelined) ----------------
// q,k hi/lo: [BH][L][128]; vt: [BH][128][L]; out: [B*L][D] f16
__global__ __launch_bounds__(256) void k_attn(const f16* __restrict__ q_hi,
                                              const f16* __restrict__ q_lo,
                                              const f16* __restrict__ k_hi,
                                              const f16* __restrict__ k_lo,
                                              const f16* __restrict__ vtp,
                                              f16* __restrict__ op) {
  __shared__ __attribute__((aligned(16))) f16 Ks_hi[64 * 136];
  __shared__ __attribute__((aligned(16))) f16 Ks_lo[64 * 136];
  __shared__ __attribute__((aligned(16))) f16 Vs[128 * 80];
  __shared__ __attribute__((aligned(16))) f16 Ps[4][16 * 80];
  const int t = threadIdx.x, l = t & 63, w = t >> 6;
  const int qt = 31 - (int)blockIdx.x;  // heavy blocks first
  const int bh = blockIdx.y;
  const int q0 = qt * 64;
  const int lr = l & 15, lq = l >> 4;

  const f16* qhp = q_hi + (size_t)bh * 2048 * 128;
  const f16* qlp = q_lo + (size_t)bh * 2048 * 128;
  const f16* khp = k_hi + (size_t)bh * 2048 * 128;
  const f16* klp = k_lo + (size_t)bh * 2048 * 128;
  const f16* vhp = vtp + (size_t)bh * 128 * 2048;

  const int krow = t >> 4, kcol8 = 8 * (t & 15);  // K stage: 16 rows/pass, 128 cols
  const int vrow = t >> 3, vcol8 = 8 * (t & 7);   // V stage: 32 rows/pass, 64 cols

  f16x8 aq_hi[4], aq_lo[4];
#pragma unroll
  for (int c = 0; c < 4; ++c) {
    const size_t qi = (size_t)(q0 + w * 16 + lr) * 128 + c * 32 + 8 * lq;
    aq_hi[c] = *(const f16x8*)&qhp[qi];
    aq_lo[c] = *(const f16x8*)&qlp[qi];
  }

  f32x4 acc[8] = {};
  float mrun[4], srun[4];
#pragma unroll
  for (int r = 0; r < 4; ++r) { mrun[r] = -1e30f; srun[r] = 0.f; }

  // prefetch registers for the next K/V tile (T14 pipeline)
  f16x8 kreg_hi[4], kreg_lo[4], vreg[4];
  auto load_tile = [&](int kt) {
#pragma unroll
    for (int i = 0; i < 4; ++i) {
      const size_t ki = (size_t)(kt * 64 + i * 16 + krow) * 128 + kcol8;
      kreg_hi[i] = *(const f16x8*)&khp[ki];
      kreg_lo[i] = *(const f16x8*)&klp[ki];
      vreg[i] = *(const f16x8*)&vhp[(size_t)(i * 32 + vrow) * 2048 + kt * 64 + vcol8];
    }
  };
  load_tile(0);

  for (int kt = 0; kt <= qt; ++kt) {
    __syncthreads();  // prior tile's LDS reads done
#pragma unroll
    for (int i = 0; i < 4; ++i) {
      const int li = (i * 16 + krow) * 136 + kcol8;
      *(f16x8*)&Ks_hi[li] = kreg_hi[i];
      *(f16x8*)&Ks_lo[li] = kreg_lo[i];
      *(f16x8*)&Vs[(i * 32 + vrow) * 80 + vcol8] = vreg[i];
    }
    __syncthreads();
    if (kt < qt) load_tile(kt + 1);  // overlap next-tile HBM latency with compute

    // S = Q K^T (split 3-pass: qh*kh + ql*kh + qh*kl; hi/lo accum split for ILP)
    f32x4 s[4];
    __builtin_amdgcn_s_setprio(1);
#pragma unroll
    for (int nt = 0; nt < 4; ++nt) {
      f32x4 zh = {}, zl = {};
#pragma unroll
      for (int kc = 0; kc < 4; ++kc) {
        const int li = (nt * 16 + lr) * 136 + kc * 32 + 8 * lq;
        f16x8 bh_ = *(const f16x8*)&Ks_hi[li];
        f16x8 bl_ = *(const f16x8*)&Ks_lo[li];
        zh = __builtin_amdgcn_mfma_f32_16x16x32_f16(aq_hi[kc], bh_, zh, 0, 0, 0);
        zl = __builtin_amdgcn_mfma_f32_16x16x32_f16(aq_lo[kc], bh_, zl, 0, 0, 0);
        zl = __builtin_amdgcn_mfma_f32_16x16x32_f16(aq_hi[kc], bl_, zl, 0, 0, 0);
      }
#pragma unroll
      for (int r = 0; r < 4; ++r) s[nt][r] = zh[r] + zl[r];
    }
    __builtin_amdgcn_s_setprio(0);
    if (kt == qt) {  // diagonal tile: causal mask
#pragma unroll
      for (int nt = 0; nt < 4; ++nt)
#pragma unroll
        for (int r = 0; r < 4; ++r) {
          const int key = kt * 64 + nt * 16 + lr;
          const int qr = q0 + w * 16 + lq * 4 + r;
          if (key > qr) s[nt][r] = -1e30f;
        }
    }
    // online softmax (rows live in 16-lane groups; reduce via shfl_xor)
    float mnew[4], scale[4], tsum[4];
#pragma unroll
    for (int r = 0; r < 4; ++r) {
      float mx = fmaxf(fmaxf(s[0][r], s[1][r]), fmaxf(s[2][r], s[3][r]));
#pragma unroll
      for (int off = 1; off < 16; off <<= 1)
        mx = fmaxf(mx, __shfl_xor(mx, off));
      mnew[r] = fmaxf(mrun[r], mx);
      scale[r] = __expf(mrun[r] - mnew[r]);
      mrun[r] = mnew[r];
      tsum[r] = 0.f;
    }
#pragma unroll
    for (int nt = 0; nt < 4; ++nt)
#pragma unroll
      for (int r = 0; r < 4; ++r) {
        const float p = __expf(s[nt][r] - mnew[r]);
        tsum[r] += p;
        Ps[w][(lq * 4 + r) * 80 + nt * 16 + lr] = (f16)p;
      }
#pragma unroll
    for (int r = 0; r < 4; ++r) {
      float ts = tsum[r];
#pragma unroll
      for (int off = 1; off < 16; off <<= 1)
        ts += __shfl_xor(ts, off);
      srun[r] = srun[r] * scale[r] + ts;
    }
#pragma unroll
    for (int nt = 0; nt < 8; ++nt)
#pragma unroll
      for (int r = 0; r < 4; ++r)
        acc[nt][r] *= scale[r];
    // O += P V
    __builtin_amdgcn_s_setprio(1);
#pragma unroll
    for (int kc = 0; kc < 2; ++kc) {
      f16x8 ap = *(const f16x8*)&Ps[w][lr * 80 + kc * 32 + 8 * lq];
#pragma unroll
      for (int nt = 0; nt < 8; ++nt) {
        f16x8 bv = *(const f16x8*)&Vs[(nt * 16 + lr) * 80 + kc * 32 + 8 * lq];
        acc[nt] = __builtin_amdgcn_mfma_f32_16x16x32_f16(ap, bv, acc[nt], 0, 0, 0);
      }
    }
    __builtin_amdgcn_s_setprio(0);
  }
  const int bb = bh >> 4, hh = bh & 15;
#pragma unroll
  for (int r = 0; r < 4; ++r) {
    const float inv = 1.f / srun[r];
    const size_t row = (size_t)(bb * 2048 + q0 + w * 16 + lq * 4 + r);
#pragma unroll
    for (int nt = 0; nt < 8; ++nt)
      op[row * 2048 + hh * 128 + nt * 16 + lr] = (f16)(acc[nt][r] * inv);
  }
}

extern "C" void kernel_launch(void* const* d_in, const int* in_sizes, int n_in,
                              void* d_out, int out_size, void* d_ws, size_t ws_size,
                              hipStream_t stream) {
  const float* x   = (const float*)d_in[0];
  const float* Wq  = (const float*)d_in[2];
  const float* Wk  = (const float*)d_in[3];
  const float* Wv  = (const float*)d_in[4];
  const float* Wo  = (const float*)d_in[5];
  const float* Wup = (const float*)d_in[6];
  const float* bup = (const float*)d_in[7];
  const float* Wdn = (const float*)d_in[8];
  float* out = (float*)d_out;

  const size_t M1 = 1u << 20;
  f16* W = (f16*)d_ws;
  // workspace layout (units of M1 f16 elems); overlays reuse dead regions:
  //  [0..8)    x_hi                      dead after V-proj
  //  [8..16)   x_lo (dead after QK)  ->  x1b (written at Wo)
  //  [16..32)  wqk_hi+wqk_lo (dead after QK) -> p0 (f32, 8M floats)
  //  [32..48)  qk_hi  (Q at 32, K at 40; dead after attn) -> hb low half
  //  [48..64)  qk_lo  (Q at 48, K at 56; dead after attn) -> hb high half
  //  [64..68)  wv_hi;  [68..72) wo_hi
  //  [72..88)  wup_hi (dead after Up) -> p1 (f32, 8M floats)
  //  [88..104) wdn_hi
  //  [104..112) vp (V proj; later attn out)
  //  [112..120) vtb (V transposed; dead after attn)
  f16* x_hi   = W + 0 * M1;
  f16* x_lo   = W + 8 * M1;
  f16* wqk_hi = W + 16 * M1;
  f16* wqk_lo = W + 24 * M1;
  f16* qk_hi  = W + 32 * M1;
  f16* qk_lo  = W + 48 * M1;
  f16* wv_hi  = W + 64 * M1;
  f16* wo_hi  = W + 68 * M1;
  f16* wup_hi = W + 72 * M1;
  f16* wdn_hi = W + 88 * M1;
  f16* vp     = W + 104 * M1;
  f16* vtb    = W + 112 * M1;
  // overlays:
  f16* x1b   = x_lo;
  float* p0  = (float*)(W + 16 * M1);
  f16* hb    = W + 32 * M1;
  float* p1  = (float*)(W + 72 * M1);
  f16* attno = vp;
  if (ws_size < (size_t)120 * M1 * sizeof(f16)) return;  // 240 MB

  auto cg = [](size_t n4) { size_t g = (n4 + 255) / 256; return (unsigned)(g > 2048 ? 2048 : g); };
  dim3 b256(256);
  k_cast2<<<cg(2 * M1), b256, 0, stream>>>(x, x_hi, x_lo, (int)(2 * M1));
  k_cast2<<<cg(1 * M1), b256, 0, stream>>>(Wq, wqk_hi, wqk_lo, (int)(1 * M1));
  k_cast2<<<cg(1 * M1), b256, 0, stream>>>(Wk, wqk_hi + 4 * M1, wqk_lo + 4 * M1, (int)(1 * M1));
  k_cast<<<cg(1 * M1), b256, 0, stream>>>(Wv, wv_hi, (int)(1 * M1));
  k_cast<<<cg(1 * M1), b256, 0, stream>>>(Wo, wo_hi, (int)(1 * M1));
  k_cast<<<cg(4 * M1), b256, 0, stream>>>(Wup, wup_hi, (int)(4 * M1));
  k_cast<<<cg(4 * M1), b256, 0, stream>>>(Wdn, wdn_hi, (int)(4 * M1));

  // fused Q+K projection (split 3-pass), N=4096 -> 1024 blocks
  gemm_nt<0, 1, 32><<<dim3(32, 32), b256, 0, stream>>>(
      x_hi, x_lo, wqk_hi, wqk_lo, 2048, 2048, 4096,
      nullptr, nullptr, nullptr, nullptr, qk_hi, qk_lo);
  // V projection
  gemm_nt<0, 0, 64><<<dim3(16, 32), b256, 0, stream>>>(
      x_hi, nullptr, wv_hi, nullptr, 2048, 2048, 2048,
      nullptr, nullptr, nullptr, nullptr, vp, nullptr);
  k_transpose_v<<<dim3(32, 2, 32), b256, 0, stream>>>(vp, vtb);
  k_attn<<<dim3(32, 32), b256, 0, stream>>>(
      qk_hi, qk_lo, qk_hi + 8 * M1, qk_lo + 8 * M1, vtb, attno);
  // Wo projection + residual -> x1b (f16)
  gemm_nt<1, 0, 64><<<dim3(16, 32), b256, 0, stream>>>(
      attno, nullptr, wo_hi, nullptr, 2048, 2048, 2048,
      x, nullptr, nullptr, nullptr, x1b, nullptr);
  // Up + bias + relu -> hb
  gemm_nt<2, 0, 64><<<dim3(64, 32), b256, 0, stream>>>(
      x1b, nullptr, wup_hi, nullptr, 2048, 2048, 8192,
      nullptr, bup, nullptr, nullptr, hb, nullptr);
  // Down, K split 2x -> f32 partials
  gemm_nt<3, 0, 64><<<dim3(16, 32, 2), b256, 0, stream>>>(
      hb, nullptr, wdn_hi, nullptr, 4096, 8192, 2048,
      nullptr, nullptr, p0, p1, nullptr, nullptr);
  // out = f32(x1b) + p0 + p1
  k_fuseout<<<2048, b256, 0, stream>>>(x1b, p0, p1, out, (int)(2 * M1));
}

// Round 8
// 840.181 us; speedup vs baseline: 1.2716x; 1.1528x over previous
//
#include <hip/hip_runtime.h>
#include <stdint.h>

typedef _Float16 f16;
typedef __attribute__((ext_vector_type(8))) _Float16 f16x8;
typedef __attribute__((ext_vector_type(4))) _Float16 f16x4;
typedef __attribute__((ext_vector_type(4))) float f32x4;

// async global->LDS, 16B per lane. LDS dest is wave-uniform base (+lane*16 in HW).
__device__ __forceinline__ void gload16(void* lds, const void* gc) {
  void* g = const_cast<void*>(gc);
  __builtin_amdgcn_global_load_lds((__attribute__((address_space(1))) void*)g,
                                   (__attribute__((address_space(3))) void*)lds,
                                   16, 0, 0);
}

// ---------------- f32 -> f16 cast (plain) ----------------
__global__ __launch_bounds__(256) void k_cast(const float* __restrict__ in,
                                              f16* __restrict__ out, int n4) {
  int stride = gridDim.x * blockDim.x;
  for (int i = blockIdx.x * blockDim.x + threadIdx.x; i < n4; i += stride) {
    float4 v = ((const float4*)in)[i];
    f16x4 o;
    o[0] = (f16)v.x; o[1] = (f16)v.y; o[2] = (f16)v.z; o[3] = (f16)v.w;
    ((f16x4*)out)[i] = o;
  }
}

// ---------------- V transpose: [BH][L][128] -> [BH][128][L] ----------------
__global__ __launch_bounds__(256) void k_transpose_v(const f16* __restrict__ vp,
                                                     f16* __restrict__ vt) {
  __shared__ __attribute__((aligned(16))) f16 tile[64][66];
  const int lt = blockIdx.x, dt = blockIdx.y, bh = blockIdx.z;
  const int t = threadIdx.x;
  const int r = t >> 3, c = 8 * (t & 7);
  const f16* src = vp + ((size_t)bh * 2048 + lt * 64) * 128 + dt * 64;
#pragma unroll
  for (int i = 0; i < 2; ++i) {
    union { f16x8 v; unsigned u[4]; } uu;
    uu.v = *(const f16x8*)&src[(size_t)(i * 32 + r) * 128 + c];
#pragma unroll
    for (int j = 0; j < 4; ++j)
      *(unsigned*)&tile[i * 32 + r][c + 2 * j] = uu.u[j];
  }
  __syncthreads();
  f16* dst = vt + ((size_t)bh * 128 + dt * 64) * 2048 + lt * 64;
#pragma unroll
  for (int i = 0; i < 2; ++i) {
    const int dr = i * 32 + r;
    f16x8 o;
#pragma unroll
    for (int e = 0; e < 8; ++e) o[e] = tile[c + e][dr];
    *(f16x8*)&dst[(size_t)dr * 2048 + c] = o;
  }
}

// ---------------- final fuse: out = f32(x1b) + p0 + p1 ----------------
__global__ __launch_bounds__(256) void k_fuseout(const f16* __restrict__ x1b,
                                                 const float* __restrict__ p0,
                                                 const float* __restrict__ p1,
                                                 float* __restrict__ out, int n4) {
  int stride = gridDim.x * blockDim.x;
  for (int i = blockIdx.x * blockDim.x + threadIdx.x; i < n4; i += stride) {
    float4 a = ((const float4*)p0)[i];
    float4 b = ((const float4*)p1)[i];
    f16x4 xb = ((const f16x4*)x1b)[i];
    float4 o;
    o.x = (float)xb[0] + a.x + b.x;
    o.y = (float)xb[1] + a.y + b.y;
    o.z = (float)xb[2] + a.z + b.z;
    o.w = (float)xb[3] + a.w + b.w;
    ((float4*)out)[i] = o;
  }
}

// ---------------- NT GEMM: C[M,N] = A[M,K] @ B[N,K]^T, fused epilogues ----------------
// EPI 0: QKV -> which=gcol>>11: 0,1 -> outb/outb_lo (hi+lo split storage) at
//        which*8M in [B,H,L,DH] layout; 2 -> outv (plain f16) same layout.
// EPI 1: Wo   -> outb = f16(res[idx] + C)
// EPI 2: Up   -> outb = f16(relu(C + bias[col]))
// EPI 3: Down partial -> (z ? outf2 : outf)[idx] = C   (f32, no residual)
// Kit = K per block; ld = row stride of A and B; blockIdx.z selects K-chunk.
template <int EPI, int SPLITOUT, int BK>
__global__ __launch_bounds__(256, 4) void gemm_nt(const f16* __restrict__ A,
                                                  const f16* __restrict__ B,
                                                  int Kit, int ld, int N,
                                                  const float* __restrict__ res,
                                                  const float* __restrict__ bias,
                                                  float* __restrict__ outf,
                                                  float* __restrict__ outf2,
                                                  f16* __restrict__ outb,
                                                  f16* __restrict__ outb_lo,
                                                  f16* __restrict__ outv) {
  constexpr int TSZ = 128 * BK;       // tile elems per matrix
  constexpr int CH  = 2048;           // elems staged per chunk (256 thr x 8)
  constexpr int RPC = CH / BK;        // rows per chunk
  constexpr int NCH = 128 / RPC;      // chunks per tile
  constexpr int CW  = BK / 8;         // threads per staged row
  __shared__ __attribute__((aligned(16))) f16 As[TSZ];
  __shared__ __attribute__((aligned(16))) f16 Bs[TSZ];
  const int t = threadIdx.x;
  const int l = t & 63;
  const int w = t >> 6;
  const int wr = w >> 1, wc = w & 1;

  // XCD-aware bijective swizzle (nwg % 8 == 0 for all our grids)
  const int nwg = gridDim.x * gridDim.y;
  const int id = blockIdx.y * gridDim.x + blockIdx.x;
  const int sw = (id & 7) * (nwg >> 3) + (id >> 3);
  const int bn = sw % gridDim.x;
  const int bm = sw / gridDim.x;
  const int k0 = blockIdx.z * Kit;

  f32x4 acc[4][4] = {};

  const size_t aoff = (size_t)bm * 128 * ld + k0;
  const size_t boff = (size_t)bn * 128 * ld + k0;

  const int sr = t / CW;            // staged row within chunk
  const int sc = 8 * (t % CW);      // staged col
  const int lbase = w * 512;        // wave-uniform LDS elem offset

  const int lr = l & 15, lq = l >> 4;
  const int nk = Kit / BK;
  for (int kt = 0; kt < nk; ++kt) {
    const size_t gbase = (size_t)kt * BK + (size_t)sr * ld + sc;
#pragma unroll
    for (int j = 0; j < NCH; ++j) {
      gload16(As + j * CH + lbase, A + aoff + (size_t)j * RPC * ld + gbase);
      gload16(Bs + j * CH + lbase, B + boff + (size_t)j * RPC * ld + gbase);
    }
    __syncthreads();
#pragma unroll
    for (int kk = 0; kk < BK / 32; ++kk) {
      f16x8 af[4], bfr[4];
#pragma unroll
      for (int m = 0; m < 4; ++m)
        af[m] = *(const f16x8*)&As[(wr * 64 + m * 16 + lr) * BK + kk * 32 + 8 * lq];
#pragma unroll
      for (int n = 0; n < 4; ++n)
        bfr[n] = *(const f16x8*)&Bs[(wc * 64 + n * 16 + lr) * BK + kk * 32 + 8 * lq];
#pragma unroll
      for (int m = 0; m < 4; ++m)
#pragma unroll
        for (int n = 0; n < 4; ++n)
          acc[m][n] = __builtin_amdgcn_mfma_f32_16x16x32_f16(af[m], bfr[n], acc[m][n], 0, 0, 0);
    }
    __syncthreads();
  }

  const size_t QKS = (size_t)8 << 20;  // stride between fused output matrices
#pragma unroll
  for (int m = 0; m < 4; ++m) {
#pragma unroll
    for (int r = 0; r < 4; ++r) {
      const int grow = bm * 128 + wr * 64 + m * 16 + lq * 4 + r;
#pragma unroll
      for (int n = 0; n < 4; ++n) {
        const int gcol = bn * 128 + wc * 64 + n * 16 + lr;
        const float v = acc[m][n][r];
        if constexpr (EPI == 0) {
          const int which = gcol >> 11;   // wave-uniform (block never straddles)
          const int hcol = gcol & 2047;
          const int bb = grow >> 11, ll = grow & 2047;
          const int hh = hcol >> 7, dh = hcol & 127;
          const size_t idx = ((size_t)((bb * 16 + hh) * 2048 + ll) << 7) + dh;
          const f16 hv = (f16)v;
          if (which == 2) {
            outv[idx] = hv;
          } else {
            outb[which * QKS + idx] = hv;
            if constexpr (SPLITOUT) outb_lo[which * QKS + idx] = (f16)(v - (float)hv);
          }
        } else if constexpr (EPI == 1) {
          const size_t idx = (size_t)grow * N + gcol;
          outb[idx] = (f16)(res[idx] + v);
        } else if constexpr (EPI == 2) {
          const size_t idx = (size_t)grow * N + gcol;
          outb[idx] = (f16)fmaxf(v + bias[gcol], 0.f);
        } else {
          const size_t idx = (size_t)grow * N + gcol;
          (blockIdx.z ? outf2 : outf)[idx] = v;
        }
      }
    }
  }
}

// ---------------- causal flash attention (split-precision QK^T, paired q-tiles) ----------------
// q,k hi/lo: [BH][L][128]; vt: [BH][128][L]; out: [B*L][D] f16
// Block bx handles q-tiles qtA=31-bx (16..31) and qtB=bx (15..0): qtA+qtB=31,
// so every block does exactly 33 tile-work-units -> perfect load balance, and
// each staged K/V tile feeds 128 q-rows.
__global__ __launch_bounds__(256) void k_attn(const f16* __restrict__ q_hi,
                                              const f16* __restrict__ q_lo,
                                              const f16* __restrict__ k_hi,
                                              const f16* __restrict__ k_lo,
                                              const f16* __restrict__ vtp,
                                              f16* __restrict__ op) {
  __shared__ __attribute__((aligned(16))) f16 Ks_hi[64 * 136];
  __shared__ __attribute__((aligned(16))) f16 Ks_lo[64 * 136];
  __shared__ __attribute__((aligned(16))) f16 Vs[128 * 72];
  __shared__ __attribute__((aligned(16))) f16 Ps[4][16 * 72];
  const int t = threadIdx.x, l = t & 63, w = t >> 6;
  const int qtA = 31 - (int)blockIdx.x;  // 16..31
  const int qtB = (int)blockIdx.x;       // 15..0
  const int bh = blockIdx.y;
  const int qA0 = qtA * 64, qB0 = qtB * 64;
  const int lr = l & 15, lq = l >> 4;

  const f16* qhp = q_hi + (size_t)bh * 2048 * 128;
  const f16* qlp = q_lo + (size_t)bh * 2048 * 128;
  const f16* khp = k_hi + (size_t)bh * 2048 * 128;
  const f16* klp = k_lo + (size_t)bh * 2048 * 128;
  const f16* vhp = vtp + (size_t)bh * 128 * 2048;

  const int krow = t >> 4, kcol8 = 8 * (t & 15);  // K stage: 16 rows/pass
  const int vrow = t >> 3, vcol8 = 8 * (t & 7);   // V stage: 32 rows/pass

  f16x8 aqhA[4], aqlA[4], aqhB[4], aqlB[4];
#pragma unroll
  for (int c = 0; c < 4; ++c) {
    const size_t qiA = (size_t)(qA0 + w * 16 + lr) * 128 + c * 32 + 8 * lq;
    const size_t qiB = (size_t)(qB0 + w * 16 + lr) * 128 + c * 32 + 8 * lq;
    aqhA[c] = *(const f16x8*)&qhp[qiA];
    aqlA[c] = *(const f16x8*)&qlp[qiA];
    aqhB[c] = *(const f16x8*)&qhp[qiB];
    aqlB[c] = *(const f16x8*)&qlp[qiB];
  }

  f32x4 accA[8] = {}, accB[8] = {};
  float mrA[4], srA[4], mrB[4], srB[4];
#pragma unroll
  for (int r = 0; r < 4; ++r) {
    mrA[r] = -1e30f; srA[r] = 0.f;
    mrB[r] = -1e30f; srB[r] = 0.f;
  }

  f16x8 kregh[4], kregl[4], vreg[4];
  auto load_tile = [&](int kt) {
#pragma unroll
    for (int i = 0; i < 4; ++i) {
      const size_t ki = (size_t)(kt * 64 + i * 16 + krow) * 128 + kcol8;
      kregh[i] = *(const f16x8*)&khp[ki];
      kregl[i] = *(const f16x8*)&klp[ki];
      vreg[i] = *(const f16x8*)&vhp[(size_t)(i * 32 + vrow) * 2048 + kt * 64 + vcol8];
    }
  };
  load_tile(0);

  auto process = [&](const f16x8 (&aqh)[4], const f16x8 (&aql)[4],
                     f32x4 (&acc)[8], float (&mr)[4], float (&sr)[4],
                     int kt, int qt, int q0) {
    // S = Q K^T (split 3-pass: qh*kh + ql*kh + qh*kl; hi/lo accum split for ILP)
    f32x4 s[4];
    __builtin_amdgcn_s_setprio(1);
#pragma unroll
    for (int nt = 0; nt < 4; ++nt) {
      f32x4 zh = {}, zl = {};
#pragma unroll
      for (int kc = 0; kc < 4; ++kc) {
        const int li = (nt * 16 + lr) * 136 + kc * 32 + 8 * lq;
        f16x8 bh_ = *(const f16x8*)&Ks_hi[li];
        f16x8 bl_ = *(const f16x8*)&Ks_lo[li];
        zh = __builtin_amdgcn_mfma_f32_16x16x32_f16(aqh[kc], bh_, zh, 0, 0, 0);
        zl = __builtin_amdgcn_mfma_f32_16x16x32_f16(aql[kc], bh_, zl, 0, 0, 0);
        zl = __builtin_amdgcn_mfma_f32_16x16x32_f16(aqh[kc], bl_, zl, 0, 0, 0);
      }
#pragma unroll
      for (int r = 0; r < 4; ++r) s[nt][r] = zh[r] + zl[r];
    }
    __builtin_amdgcn_s_setprio(0);
    if (kt == qt) {  // diagonal tile: causal mask
#pragma unroll
      for (int nt = 0; nt < 4; ++nt)
#pragma unroll
        for (int r = 0; r < 4; ++r) {
          const int key = kt * 64 + nt * 16 + lr;
          const int qr = q0 + w * 16 + lq * 4 + r;
          if (key > qr) s[nt][r] = -1e30f;
        }
    }
    // online softmax (rows live in 16-lane groups; reduce via shfl_xor)
    float mnew[4], scale[4], tsum[4];
#pragma unroll
    for (int r = 0; r < 4; ++r) {
      float mx = fmaxf(fmaxf(s[0][r], s[1][r]), fmaxf(s[2][r], s[3][r]));
#pragma unroll
      for (int off = 1; off < 16; off <<= 1)
        mx = fmaxf(mx, __shfl_xor(mx, off));
      mnew[r] = fmaxf(mr[r], mx);
      scale[r] = __expf(mr[r] - mnew[r]);
      mr[r] = mnew[r];
      tsum[r] = 0.f;
    }
#pragma unroll
    for (int nt = 0; nt < 4; ++nt)
#pragma unroll
      for (int r = 0; r < 4; ++r) {
        const float p = __expf(s[nt][r] - mnew[r]);
        tsum[r] += p;
        Ps[w][(lq * 4 + r) * 72 + nt * 16 + lr] = (f16)p;
      }
#pragma unroll
    for (int r = 0; r < 4; ++r) {
      float ts = tsum[r];
#pragma unroll
      for (int off = 1; off < 16; off <<= 1)
        ts += __shfl_xor(ts, off);
      sr[r] = sr[r] * scale[r] + ts;
    }
#pragma unroll
    for (int nt = 0; nt < 8; ++nt)
#pragma unroll
      for (int r = 0; r < 4; ++r)
        acc[nt][r] *= scale[r];
    // O += P V
    __builtin_amdgcn_s_setprio(1);
#pragma unroll
    for (int kc = 0; kc < 2; ++kc) {
      f16x8 ap = *(const f16x8*)&Ps[w][lr * 72 + kc * 32 + 8 * lq];
#pragma unroll
      for (int nt = 0; nt < 8; ++nt) {
        f16x8 bv = *(const f16x8*)&Vs[(nt * 16 + lr) * 72 + kc * 32 + 8 * lq];
        acc[nt] = __builtin_amdgcn_mfma_f32_16x16x32_f16(ap, bv, acc[nt], 0, 0, 0);
      }
    }
    __builtin_amdgcn_s_setprio(0);
  };

  for (int kt = 0; kt <= qtA; ++kt) {
    __syncthreads();  // prior tile's LDS reads done
#pragma unroll
    for (int i = 0; i < 4; ++i) {
      const int li = (i * 16 + krow) * 136 + kcol8;
      *(f16x8*)&Ks_hi[li] = kregh[i];
      *(f16x8*)&Ks_lo[li] = kregl[i];
      *(f16x8*)&Vs[(i * 32 + vrow) * 72 + vcol8] = vreg[i];
    }
    __syncthreads();
    if (kt < qtA) load_tile(kt + 1);  // next-tile HBM latency hides under compute
    process(aqhA, aqlA, accA, mrA, srA, kt, qtA, qA0);
    if (kt <= qtB) process(aqhB, aqlB, accB, mrB, srB, kt, qtB, qB0);
  }

  const int bb = bh >> 4, hh = bh & 15;
  auto wout = [&](f32x4 (&acc)[8], float (&sr)[4], int q0) {
#pragma unroll
    for (int r = 0; r < 4; ++r) {
      const float inv = 1.f / sr[r];
      const size_t row = (size_t)(bb * 2048 + q0 + w * 16 + lq * 4 + r);
#pragma unroll
      for (int nt = 0; nt < 8; ++nt)
        op[row * 2048 + hh * 128 + nt * 16 + lr] = (f16)(acc[nt][r] * inv);
    }
  };
  wout(accA, srA, qA0);
  wout(accB, srB, qB0);
}

extern "C" void kernel_launch(void* const* d_in, const int* in_sizes, int n_in,
                              void* d_out, int out_size, void* d_ws, size_t ws_size,
                              hipStream_t stream) {
  const float* x   = (const float*)d_in[0];
  const float* Wq  = (const float*)d_in[2];
  const float* Wk  = (const float*)d_in[3];
  const float* Wv  = (const float*)d_in[4];
  const float* Wo  = (const float*)d_in[5];
  const float* Wup = (const float*)d_in[6];
  const float* bup = (const float*)d_in[7];
  const float* Wdn = (const float*)d_in[8];
  float* out = (float*)d_out;

  const size_t M1 = 1u << 20;
  f16* W = (f16*)d_ws;
  // workspace layout (units of M1 f16 elems); overlays reuse dead regions:
  //  [0..8)    x_hi (dead after QKV gemm)     -> x1b overlay (live to fuseout)
  //  [8..20)   wqkv_hi (dead after QKV)
  //  [20..24)  wo_hi (dead after Wo)
  //  [24..40)  wup_hi (dead after Up)         -> p0 overlay (8M floats)
  //  [40..56)  wdn_hi (live to Down)
  //  [56..64)  q_hi (dead after attn)         -> hb overlay [56..88)
  //  [64..72)  k_hi (dead after attn)
  //  [72..80)  q_lo (dead after attn)
  //  [80..88)  k_lo (dead after attn)
  //  [88..96)  vp (V proj; attn out; dead after Wo)  -> p1 overlay [88..104)
  //  [96..104) vtb (dead after attn)
  f16* x_hi    = W + 0 * M1;
  f16* wqkv_hi = W + 8 * M1;
  f16* wo_hi   = W + 20 * M1;
  f16* wup_hi  = W + 24 * M1;
  f16* wdn_hi  = W + 40 * M1;
  f16* q_hi    = W + 56 * M1;
  f16* q_lo    = W + 72 * M1;
  f16* vp      = W + 88 * M1;
  f16* vtb     = W + 96 * M1;
  // overlays (checked against live sets per stage):
  f16* x1b   = x_hi;                  // [0..8)  written by Wo, read by Up+fuseout
  float* p0  = (float*)(W + 24 * M1); // [24..40) — wup dead at Down
  f16* hb    = W + 56 * M1;           // [56..88) — q/k hi/lo dead after attn
  float* p1  = (float*)(W + 88 * M1); // [88..104) — vp/vtb dead after Wo; NO hb overlap
  f16* attno = vp;
  if (ws_size < (size_t)104 * M1 * sizeof(f16)) return;  // 208 MB

  auto cg = [](size_t n4) { size_t g = (n4 + 255) / 256; return (unsigned)(g > 2048 ? 2048 : g); };
  dim3 b256(256);
  k_cast<<<cg(2 * M1), b256, 0, stream>>>(x, x_hi, (int)(2 * M1));
  k_cast<<<cg(1 * M1), b256, 0, stream>>>(Wq, wqkv_hi, (int)(1 * M1));
  k_cast<<<cg(1 * M1), b256, 0, stream>>>(Wk, wqkv_hi + 4 * M1, (int)(1 * M1));
  k_cast<<<cg(1 * M1), b256, 0, stream>>>(Wv, wqkv_hi + 8 * M1, (int)(1 * M1));
  k_cast<<<cg(1 * M1), b256, 0, stream>>>(Wo, wo_hi, (int)(1 * M1));
  k_cast<<<cg(4 * M1), b256, 0, stream>>>(Wup, wup_hi, (int)(4 * M1));
  k_cast<<<cg(4 * M1), b256, 0, stream>>>(Wdn, wdn_hi, (int)(4 * M1));

  // fused Q+K+V projection: single-pass f16, split (hi+lo) OUTPUT for Q,K.
  // q_hi at 56M, k_hi at 64M (stride 8M = QKS); q_lo at 72M, k_lo at 80M.
  gemm_nt<0, 1, 64><<<dim3(48, 32), b256, 0, stream>>>(
      x_hi, wqkv_hi, 2048, 2048, 6144,
      nullptr, nullptr, nullptr, nullptr, q_hi, q_lo, vp);
  k_transpose_v<<<dim3(32, 2, 32), b256, 0, stream>>>(vp, vtb);
  k_attn<<<dim3(16, 32), b256, 0, stream>>>(
      q_hi, q_lo, q_hi + 8 * M1, q_lo + 8 * M1, vtb, attno);
  // Wo projection + residual -> x1b (f16)
  gemm_nt<1, 0, 64><<<dim3(16, 32), b256, 0, stream>>>(
      attno, wo_hi, 2048, 2048, 2048,
      x, nullptr, nullptr, nullptr, x1b, nullptr, nullptr);
  // Up + bias + relu -> hb
  gemm_nt<2, 0, 64><<<dim3(64, 32), b256, 0, stream>>>(
      x1b, wup_hi, 2048, 2048, 8192,
      nullptr, bup, nullptr, nullptr, hb, nullptr, nullptr);
  // Down, K split 2x -> f32 partials
  gemm_nt<3, 0, 64><<<dim3(16, 32, 2), b256, 0, stream>>>(
      hb, wdn_hi, 4096, 8192, 2048,
      nullptr, nullptr, p0, p1, nullptr, nullptr, nullptr);
  // out = f32(x1b) + p0 + p1
  k_fuseout<<<2048, b256, 0, stream>>>(x1b, p0, p1, out, (int)(2 * M1));
}